// Round 1
// 414.695 us; speedup vs baseline: 1.9034x; 1.9034x over previous
//
#include <hip/hip_runtime.h>
#include <cstdint>
#include <cstddef>

// Match numpy/XLA float32 semantics: no FMA contraction anywhere.
#pragma clang fp contract(off)

#define KCLS 9
#define PRE_N 6000
#define POST_N 300
#define POOL_N 8192
#define NMS_IOU_T 0.7f
#define HIST_BLOCK 256
#define CHUNKS_PER_IMG 32
#define NMS_BLOCK 512
#define PICK_BLOCK 256

// ---------------- stage 1: softmax over K=9 ----------------
__global__ void softmax_kernel(const float* __restrict__ labels,
                               float* __restrict__ scores, int ngroups) {
    int g = blockIdx.x * blockDim.x + threadIdx.x;
    if (g >= ngroups) return;
    const float* x = labels + (size_t)g * KCLS;
    float v[KCLS];
    float m = -1e30f;
    #pragma unroll
    for (int k = 0; k < KCLS; ++k) { v[k] = x[k]; m = fmaxf(m, v[k]); }
    float e[KCLS];
    float s = 0.f;
    #pragma unroll
    for (int k = 0; k < KCLS; ++k) { e[k] = expf(v[k] - m); s += e[k]; }
    float* o = scores + (size_t)g * KCLS;
    #pragma unroll
    for (int k = 0; k < KCLS; ++k) o[k] = e[k] / s;
}

// ---------------- stage 2a: per-pass radix histogram (full grid) ----------------
__global__ void hist_kernel(const float* __restrict__ scores,
                            unsigned int* __restrict__ ghist,        // [B][2048]
                            const unsigned int* __restrict__ state,  // [B][2] {prefix,krem}
                            int A, int shift, int bins, unsigned int pmask) {
    __shared__ unsigned int h[2048];
    const int img = blockIdx.y;
    const int chunk = blockIdx.x;
    const int tid = threadIdx.x;
    for (int i = tid; i < bins; i += HIST_BLOCK) h[i] = 0u;
    __syncthreads();
    unsigned int prefix = pmask ? (state[img * 2 + 0] & pmask) : 0u;
    const int per = A / CHUNKS_PER_IMG;
    const float* sc = scores + (size_t)img * A + (size_t)chunk * per;
    for (int i = tid; i < per; i += HIST_BLOCK) {
        unsigned int v = __float_as_uint(sc[i]);   // scores > 0: uint order == float order
        if ((v & pmask) == prefix)
            atomicAdd(&h[(v >> shift) & (unsigned)(bins - 1)], 1u);
    }
    __syncthreads();
    unsigned int* gh = ghist + (size_t)img * 2048;
    for (int i = tid; i < bins; i += HIST_BLOCK) {
        unsigned int c = h[i];
        if (c) atomicAdd(&gh[i], c);
    }
}

// ---------------- stage 2b: pick target bin (parallel suffix scan) ----------------
__global__ void __launch_bounds__(PICK_BLOCK)
pick_kernel(const unsigned int* __restrict__ ghist,
            unsigned int* __restrict__ state,
            int shift, int bins, int first_pass) {
    const int img = blockIdx.x;
    const int t = threadIdx.x;
    const unsigned int* gh = ghist + (size_t)img * 2048;
    __shared__ unsigned int cnt[2048];
    __shared__ unsigned int ssum[PICK_BLOCK];
    const int per = bins / PICK_BLOCK;   // 8 or 4
    unsigned int my = 0;
    for (int i = 0; i < per; ++i) {
        unsigned int c = gh[t * per + i];
        cnt[t * per + i] = c;
        my += c;
    }
    ssum[t] = my;
    __syncthreads();
    // inclusive suffix scan: ssum[t] = sum_{u >= t} chunk_sum[u]
    for (int d = 1; d < PICK_BLOCK; d <<= 1) {
        unsigned int v = (t + d < PICK_BLOCK) ? ssum[t + d] : 0u;
        __syncthreads();
        ssum[t] += v;
        __syncthreads();
    }
    unsigned int prefix = first_pass ? 0u : state[img * 2 + 0];
    unsigned int krem = first_pass ? (unsigned)PRE_N : state[img * 2 + 1];
    unsigned int above = ssum[t] - my;   // strictly above my chunk
    if (above < krem && ssum[t] >= krem) {   // unique thread
        unsigned int cum = above;
        for (int b = per - 1; b >= 0; --b) {
            unsigned int c = cnt[t * per + b];
            if (cum + c >= krem) {
                state[img * 2 + 0] = prefix | ((unsigned int)(t * per + b) << shift);
                state[img * 2 + 1] = krem - cum;
                break;
            }
            cum += c;
        }
    }
}

// ---------------- stage 2c: pool build + bitonic sort + decode top-6000 ----------------
__global__ void __launch_bounds__(1024)
topk_sort_kernel(const float* __restrict__ scores,
                 const float* __restrict__ deltas,   // [B][A][4]
                 const float* __restrict__ anchors,  // [A][4]
                 const unsigned int* __restrict__ state,
                 float* __restrict__ pre_boxes,      // [B][6000][4]
                 float* __restrict__ pre_scores,     // [B][6000]
                 int A) {
    extern __shared__ unsigned long long pool[];  // POOL_N entries = 64 KB
    __shared__ unsigned int cnt;                  // block-local push counter
    const int img = blockIdx.x;
    const int tid = threadIdx.x;
    const int lane = tid & 63;
    const float* sc = scores + (size_t)img * A;
    const unsigned int T = state[img * 2 + 0];  // exact bits of the 6000th-largest score

    if (tid == 0) cnt = 0u;
    // pre-fill with +inf keys; pushes overwrite [0, cnt)
    for (int i = tid; i < POOL_N; i += 1024) pool[i] = ~0ull;
    __syncthreads();

    // wave-aggregated push of all scores >= T (count(>T) <= 5999, ties included)
    for (int i = tid; i < A; i += 1024) {  // A % 1024 == 0: no tail divergence
        unsigned int v = __float_as_uint(sc[i]);
        bool push = (v >= T);
        unsigned long long bal = __ballot(push ? 1 : 0);
        if (push) {
            int leader = __ffsll(bal) - 1;
            int rank = __popcll(bal & ((1ull << lane) - 1ull));
            unsigned int base = 0;
            if (lane == leader)
                base = atomicAdd(&cnt, (unsigned int)__popcll(bal));
            base = (unsigned int)__shfl((int)base, leader);
            unsigned int pos = base + (unsigned int)rank;
            if (pos < POOL_N)
                pool[pos] = (((unsigned long long)(~v)) << 32) | (unsigned long long)(unsigned int)i;
        }
    }
    __syncthreads();

    // bitonic sort ascending: key = (~score_bits, index) -> score desc, index asc (top_k tie order)
    for (int k = 2; k <= POOL_N; k <<= 1) {
        for (int j = k >> 1; j > 0; j >>= 1) {
            #pragma unroll
            for (int s = 0; s < POOL_N / 1024; ++s) {
                int i = tid + s * 1024;
                int ixj = i ^ j;
                if (ixj > i) {
                    unsigned long long a = pool[i], b = pool[ixj];
                    bool up = ((i & k) == 0);
                    if ((a > b) == up) { pool[i] = b; pool[ixj] = a; }
                }
            }
            __syncthreads();
        }
    }

    // decode boxes for the top-6000 (reference float32 op order, no contraction)
    for (int r = tid; r < PRE_N; r += 1024) {
        unsigned long long key = pool[r];
        unsigned int idx = (unsigned int)(key & 0xFFFFFFFFull);
        unsigned int sbits = ~((unsigned int)(key >> 32));
        float score = __uint_as_float(sbits);
        float a0 = anchors[(size_t)idx * 4 + 0];
        float a1 = anchors[(size_t)idx * 4 + 1];
        float a2 = anchors[(size_t)idx * 4 + 2];
        float a3 = anchors[(size_t)idx * 4 + 3];
        const float* dd = deltas + ((size_t)img * A + idx) * 4;
        float d0 = dd[0] * 0.1f;
        float d1 = dd[1] * 0.1f;
        float d2 = dd[2] * 0.2f;
        float d3 = dd[3] * 0.2f;
        float anc_w = a3 - a1;
        float anc_h = a2 - a0;
        float anc_cx = a1 + 0.5f * anc_w;
        float anc_cy = a0 + 0.5f * anc_h;
        float bb_w = expf(d3) * anc_w;
        float bb_h = expf(d2) * anc_h;
        float bb_cx = d1 * anc_w + anc_cx;
        float bb_cy = d0 * anc_h + anc_cy;
        float y1 = bb_cy - 0.5f * bb_h;
        float x1 = bb_cx - 0.5f * bb_w;
        float y2 = bb_h + y1;
        float x2 = bb_w + x1;
        float* ob = pre_boxes + ((size_t)img * PRE_N + r) * 4;
        ob[0] = y1; ob[1] = x1; ob[2] = y2; ob[3] = x2;
        pre_scores[(size_t)img * PRE_N + r] = score;
    }
}

// ---------------- stage 3: chunked greedy NMS ----------------
// Scores are sorted desc with top_k tie order, so greedy NMS == scan boxes in
// index order, keep box j iff no previously-KEPT box suppresses it. Process in
// 94 chunks of 64:
//   phase E (all 8 waves): chunk boxes vs kept list (LDS), round-robin k=grp+8t,
//            early-break; one ballot+atomicAnd per wave into a 64-bit alive mask.
//   phase S (wave 0, no block barriers): resolve within-chunk order serially via
//            ffsll + shfl pivot broadcast + wave-wide IoU ballot.
// Only 2 block barriers per chunk (188 total) vs 600 in the per-pick design, and
// each box is IoU-tested once instead of re-swept every iteration.
// Suppression test = multiply prescreen with +-1e-6 decisive margins; exact
// reference division only in the borderline window -> bit-identical decisions
// to `inter/den > 0.7f` with reference float op order.
__global__ void __launch_bounds__(NMS_BLOCK)
nms_kernel(const float* __restrict__ pre_boxes,
           const float* __restrict__ pre_scores,
           float* __restrict__ out_boxes,    // [B][300][4] (pre-zeroed)
           float* __restrict__ out_scores) { // [B][300]
    const int img = blockIdx.x;
    const int tid = threadIdx.x;
    const int lane = tid & 63;
    const int grp = tid >> 6;                 // 0..7
    const float4* bb4 = (const float4*)(pre_boxes + (size_t)img * PRE_N * 4);

    __shared__ float4 kept[POST_N];           // kept boxes (in keep order)
    __shared__ float  kept_area[POST_N];
    __shared__ int    kept_idx[POST_N];       // global index into pre_* arrays
    __shared__ float4 chunkbox[64];
    __shared__ unsigned long long chunk_alive;
    __shared__ int kept_cnt;

    if (tid == 0) kept_cnt = 0;

    const int NCH = (PRE_N + 63) >> 6;        // 94 (last chunk: 48 valid)

    // prefetch chunk 0 (grp 0 owns staging)
    float4 nb = make_float4(0.f, 0.f, 0.f, 0.f);
    if (grp == 0) nb = bb4[lane];             // chunk 0 fully valid (64 <= 6000)

    for (int c = 0; c < NCH; ++c) {
        const int base = c << 6;
        if (grp == 0) chunkbox[lane] = nb;
        if (tid == 0) {
            int rem = PRE_N - base;
            chunk_alive = (rem >= 64) ? ~0ull : ((1ull << rem) - 1ull);
        }
        __syncthreads();

        // issue next-chunk prefetch early; latency hides under phases E+S
        if (grp == 0 && c + 1 < NCH) {
            int j = base + 64 + lane;
            nb = (j < PRE_N) ? bb4[j] : make_float4(0.f, 0.f, 0.f, 0.f);
        }

        const int K = kept_cnt;
        float4 mb = chunkbox[lane];
        float marea = (mb.z - mb.x) * (mb.w - mb.y);

        // ---- phase E: external suppression vs previously-kept boxes ----
        bool sup = false;
        for (int k = grp; k < K; k += 8) {
            float4 pb = kept[k];              // LDS broadcast (uniform addr per wave)
            float pa = kept_area[k];
            float iy1 = fmaxf(pb.x, mb.x);
            float ix1 = fmaxf(pb.y, mb.y);
            float iy2 = fminf(pb.z, mb.z);
            float ix2 = fminf(pb.w, mb.w);
            float ih = iy2 - iy1; ih = ih > 0.f ? ih : 0.f;
            float iw = ix2 - ix1; iw = iw > 0.f ? iw : 0.f;
            float inter = ih * iw;
            float den = marea + pa - inter + 1e-9f;  // ref order: ((areas+b_area)-inter)+eps
            float hi = 0.7000007f * den;
            float lo = 0.6999993f * den;
            bool s = inter > hi;
            if (inter >= lo && inter <= hi)
                s = (inter / den) > NMS_IOU_T;
            if (s) { sup = true; break; }
        }
        unsigned long long bal = __ballot(sup ? 1 : 0);
        if (lane == 0 && bal) atomicAnd(&chunk_alive, ~bal);
        __syncthreads();

        // ---- phase S: serial within-chunk resolution (wave 0 only) ----
        if (grp == 0) {
            unsigned long long m = chunk_alive;
            int kc = K;
            while (m && kc < POST_N) {
                int i = __ffsll(m) - 1;
                float py1 = __shfl(mb.x, i);
                float px1 = __shfl(mb.y, i);
                float py2 = __shfl(mb.z, i);
                float px2 = __shfl(mb.w, i);
                float pa  = __shfl(marea, i);
                if (lane == i) {
                    kept[kc] = mb;
                    kept_area[kc] = marea;
                    kept_idx[kc] = base + i;
                }
                float iy1 = fmaxf(py1, mb.x);
                float ix1 = fmaxf(px1, mb.y);
                float iy2 = fminf(py2, mb.z);
                float ix2 = fminf(px2, mb.w);
                float ih = iy2 - iy1; ih = ih > 0.f ? ih : 0.f;
                float iw = ix2 - ix1; iw = iw > 0.f ? iw : 0.f;
                float inter = ih * iw;
                float den = marea + pa - inter + 1e-9f;
                float hi = 0.7000007f * den;
                float lo = 0.6999993f * den;
                bool s = inter > hi;
                if (inter >= lo && inter <= hi)
                    s = (inter / den) > NMS_IOU_T;
                unsigned long long sb = __ballot(s ? 1 : 0);
                m &= ~sb;
                m &= ~(1ull << i);            // pivot resolved (self-IoU ~= 1 anyway)
                ++kc;
            }
            if (lane == 0) kept_cnt = kc;
        }
        __syncthreads();
        if (kept_cnt >= POST_N) break;        // uniform
    }

    // ---- write outputs (rest of the pre-zeroed buffer stays zero) ----
    const int kc = kept_cnt;
    for (int r = tid; r < kc; r += NMS_BLOCK) {
        float4 b = kept[r];
        float* ob = out_boxes + ((size_t)img * POST_N + r) * 4;
        ob[0] = b.x; ob[1] = b.y; ob[2] = b.z; ob[3] = b.w;
        out_scores[(size_t)img * POST_N + r] =
            pre_scores[(size_t)img * PRE_N + kept_idx[r]];
    }
}

extern "C" void kernel_launch(void* const* d_in, const int* in_sizes, int n_in,
                              void* d_out, int out_size, void* d_ws, size_t ws_size,
                              hipStream_t stream) {
    const float* deltas  = (const float*)d_in[0];  // (B, A, 4)
    const float* labels  = (const float*)d_in[1];  // (B, FH, FW, 9)
    const float* anchors = (const float*)d_in[2];  // (A, 4)
    float* out = (float*)d_out;

    const int A = in_sizes[2] / 4;                 // 147456
    const int B = in_sizes[0] / (A * 4);           // 32
    const int ngroups = in_sizes[1] / KCLS;        // B*FH*FW

    // workspace layout
    float* scores     = (float*)d_ws;                                // B*A
    float* pre_boxes  = scores + (size_t)B * A;                      // B*6000*4
    float* pre_scores = pre_boxes + (size_t)B * PRE_N * 4;           // B*6000
    unsigned int* hist  = (unsigned int*)(pre_scores + (size_t)B * PRE_N);  // 3*B*2048
    unsigned int* state = hist + (size_t)3 * B * 2048;               // B*2

    float* out_boxes  = out;                        // B*300*4
    float* out_scores = out + (size_t)B * POST_N * 4;

    hipMemsetAsync(d_out, 0, (size_t)out_size * sizeof(float), stream);
    hipMemsetAsync(hist, 0, (size_t)3 * B * 2048 * sizeof(unsigned int), stream);

    softmax_kernel<<<(ngroups + 255) / 256, 256, 0, stream>>>(labels, scores, ngroups);

    dim3 hgrid(CHUNKS_PER_IMG, B);
    // pass 1: bits [31:21]
    hist_kernel<<<hgrid, HIST_BLOCK, 0, stream>>>(scores, hist + (size_t)0 * B * 2048, state, A, 21, 2048, 0x00000000u);
    pick_kernel<<<B, PICK_BLOCK, 0, stream>>>(hist + (size_t)0 * B * 2048, state, 21, 2048, 1);
    // pass 2: bits [20:10]
    hist_kernel<<<hgrid, HIST_BLOCK, 0, stream>>>(scores, hist + (size_t)1 * B * 2048, state, A, 10, 2048, 0xFFE00000u);
    pick_kernel<<<B, PICK_BLOCK, 0, stream>>>(hist + (size_t)1 * B * 2048, state, 10, 2048, 0);
    // pass 3: bits [9:0]
    hist_kernel<<<hgrid, HIST_BLOCK, 0, stream>>>(scores, hist + (size_t)2 * B * 2048, state, A, 0, 1024, 0xFFFFFC00u);
    pick_kernel<<<B, PICK_BLOCK, 0, stream>>>(hist + (size_t)2 * B * 2048, state, 0, 1024, 0);

    topk_sort_kernel<<<B, 1024, POOL_N * sizeof(unsigned long long), stream>>>(
        scores, deltas, anchors, state, pre_boxes, pre_scores, A);

    nms_kernel<<<B, NMS_BLOCK, 0, stream>>>(pre_boxes, pre_scores, out_boxes, out_scores);
}

// Round 2
// 366.799 us; speedup vs baseline: 2.1519x; 1.1306x over previous
//
#include <hip/hip_runtime.h>
#include <cstdint>
#include <cstddef>

// Match numpy/XLA float32 semantics: no FMA contraction anywhere.
#pragma clang fp contract(off)

#define KCLS 9
#define PRE_N 6000
#define POST_N 300
#define POOL_N 8192
#define NMS_IOU_T 0.7f
#define HIST_BLOCK 256
#define CHUNKS_PER_IMG 32
#define NMS_BLOCK 512
#define PICK_BLOCK 256

// ---------------- stage 1: softmax over K=9 ----------------
__global__ void softmax_kernel(const float* __restrict__ labels,
                               float* __restrict__ scores, int ngroups) {
    int g = blockIdx.x * blockDim.x + threadIdx.x;
    if (g >= ngroups) return;
    const float* x = labels + (size_t)g * KCLS;
    float v[KCLS];
    float m = -1e30f;
    #pragma unroll
    for (int k = 0; k < KCLS; ++k) { v[k] = x[k]; m = fmaxf(m, v[k]); }
    float e[KCLS];
    float s = 0.f;
    #pragma unroll
    for (int k = 0; k < KCLS; ++k) { e[k] = expf(v[k] - m); s += e[k]; }
    float* o = scores + (size_t)g * KCLS;
    #pragma unroll
    for (int k = 0; k < KCLS; ++k) o[k] = e[k] / s;
}

// ---------------- stage 2a: per-pass radix histogram (full grid) ----------------
__global__ void hist_kernel(const float* __restrict__ scores,
                            unsigned int* __restrict__ ghist,        // [B][2048]
                            const unsigned int* __restrict__ state,  // [B][2] {prefix,krem}
                            int A, int shift, int bins, unsigned int pmask) {
    __shared__ unsigned int h[2048];
    const int img = blockIdx.y;
    const int chunk = blockIdx.x;
    const int tid = threadIdx.x;
    for (int i = tid; i < bins; i += HIST_BLOCK) h[i] = 0u;
    __syncthreads();
    unsigned int prefix = pmask ? (state[img * 2 + 0] & pmask) : 0u;
    const int per = A / CHUNKS_PER_IMG;
    const float* sc = scores + (size_t)img * A + (size_t)chunk * per;
    for (int i = tid; i < per; i += HIST_BLOCK) {
        unsigned int v = __float_as_uint(sc[i]);   // scores > 0: uint order == float order
        if ((v & pmask) == prefix)
            atomicAdd(&h[(v >> shift) & (unsigned)(bins - 1)], 1u);
    }
    __syncthreads();
    unsigned int* gh = ghist + (size_t)img * 2048;
    for (int i = tid; i < bins; i += HIST_BLOCK) {
        unsigned int c = h[i];
        if (c) atomicAdd(&gh[i], c);
    }
}

// ---------------- stage 2b: pick target bin (parallel suffix scan) ----------------
__global__ void __launch_bounds__(PICK_BLOCK)
pick_kernel(const unsigned int* __restrict__ ghist,
            unsigned int* __restrict__ state,
            int shift, int bins, int first_pass) {
    const int img = blockIdx.x;
    const int t = threadIdx.x;
    const unsigned int* gh = ghist + (size_t)img * 2048;
    __shared__ unsigned int cnt[2048];
    __shared__ unsigned int ssum[PICK_BLOCK];
    const int per = bins / PICK_BLOCK;   // 8 or 4
    unsigned int my = 0;
    for (int i = 0; i < per; ++i) {
        unsigned int c = gh[t * per + i];
        cnt[t * per + i] = c;
        my += c;
    }
    ssum[t] = my;
    __syncthreads();
    // inclusive suffix scan: ssum[t] = sum_{u >= t} chunk_sum[u]
    for (int d = 1; d < PICK_BLOCK; d <<= 1) {
        unsigned int v = (t + d < PICK_BLOCK) ? ssum[t + d] : 0u;
        __syncthreads();
        ssum[t] += v;
        __syncthreads();
    }
    unsigned int prefix = first_pass ? 0u : state[img * 2 + 0];
    unsigned int krem = first_pass ? (unsigned)PRE_N : state[img * 2 + 1];
    unsigned int above = ssum[t] - my;   // strictly above my chunk
    if (above < krem && ssum[t] >= krem) {   // unique thread
        unsigned int cum = above;
        for (int b = per - 1; b >= 0; --b) {
            unsigned int c = cnt[t * per + b];
            if (cum + c >= krem) {
                state[img * 2 + 0] = prefix | ((unsigned int)(t * per + b) << shift);
                state[img * 2 + 1] = krem - cum;
                break;
            }
            cum += c;
        }
    }
}

// ---------------- stage 2c: pool build + register-blocked bitonic sort + decode ----------------
// Thread t owns ranks [8t, 8t+8) in registers. Bitonic stages with j<8 are pure
// in-register CEs (no LDS, no barrier). Stages with j>=8 publish the 8 keys to
// LDS (split lo/hi u32 planes, transposed [e][1024] layout -> conflict-free),
// barrier once, read partner thread's 8 (t ^ (j>>3)), keep min/max in regs.
// Ping-pong between two 64KB buffers gives exactly 1 barrier per LDS stage.
// 55 LDS stages + 36 register stages vs 91 full-LDS passes before.
#define CE(a, b, u) { if ((v[a] > v[b]) == (u)) { unsigned long long t_ = v[a]; v[a] = v[b]; v[b] = t_; } }
#define REG3(u) { CE(0,4,u) CE(1,5,u) CE(2,6,u) CE(3,7,u) \
                  CE(0,2,u) CE(1,3,u) CE(4,6,u) CE(5,7,u) \
                  CE(0,1,u) CE(2,3,u) CE(4,5,u) CE(6,7,u) }

__global__ void __launch_bounds__(1024)
topk_sort_kernel(const float* __restrict__ scores,
                 const float* __restrict__ deltas,   // [B][A][4]
                 const float* __restrict__ anchors,  // [A][4]
                 const unsigned int* __restrict__ state,
                 float* __restrict__ pre_boxes,      // [B][6000][4]
                 float* __restrict__ pre_scores,     // [B][6000]
                 int A) {
    __shared__ unsigned int plo[2][POOL_N];   // 64 KB
    __shared__ unsigned int phi[2][POOL_N];   // 64 KB
    __shared__ unsigned int cnt;
    const int img = blockIdx.x;
    const int tid = threadIdx.x;
    const int lane = tid & 63;
    const float* sc = scores + (size_t)img * A;
    const unsigned int T = state[img * 2 + 0];  // exact bits of the 6000th-largest score

    if (tid == 0) cnt = 0u;
    // pre-fill buffer 0 with max keys; pushes overwrite [0, cnt)
    for (int i = tid; i < POOL_N; i += 1024) { plo[0][i] = ~0u; phi[0][i] = ~0u; }
    __syncthreads();

    // wave-aggregated push of all scores >= T (count(>T) <= 5999, ties included)
    for (int i = tid; i < A; i += 1024) {  // A % 1024 == 0: no tail divergence
        unsigned int sv = __float_as_uint(sc[i]);
        bool push = (sv >= T);
        unsigned long long bal = __ballot(push ? 1 : 0);
        if (push) {
            int leader = __ffsll(bal) - 1;
            int rank = __popcll(bal & ((1ull << lane) - 1ull));
            unsigned int base = 0;
            if (lane == leader)
                base = atomicAdd(&cnt, (unsigned int)__popcll(bal));
            base = (unsigned int)__shfl((int)base, leader);
            unsigned int pos = base + (unsigned int)rank;
            if (pos < POOL_N) {
                int idx = (int)(((pos & 7u) << 10) | (pos >> 3));  // transposed slot
                plo[0][idx] = (unsigned int)i;   // low word: index
                phi[0][idx] = ~sv;               // high word: ~score_bits
            }
        }
    }
    __syncthreads();

    // load my 8 consecutive elements (ranks 8t..8t+7) into registers
    unsigned long long v[8];
    #pragma unroll
    for (int e = 0; e < 8; ++e) {
        int idx = (e << 10) | tid;
        v[e] = ((unsigned long long)phi[0][idx] << 32) | (unsigned long long)plo[0][idx];
    }

    // ascending sort by key=(~score,index) -> score desc, index asc (top_k tie order)
    // k=2
    CE(0,1,true) CE(2,3,false) CE(4,5,true) CE(6,7,false)
    // k=4
    CE(0,2,true) CE(1,3,true) CE(4,6,false) CE(5,7,false)
    CE(0,1,true) CE(2,3,true) CE(4,5,false) CE(6,7,false)
    // k=8: direction uniform per thread
    {
        bool u8 = ((tid & 1) == 0);
        REG3(u8)
    }
    // k = 16 .. 8192
    int b = 1;
    for (int k = 16; k <= POOL_N; k <<= 1) {
        const bool up = (((tid << 3) & k) == 0);
        for (int j = k >> 1; j >= 8; j >>= 1) {
            const int c = j >> 3;
            #pragma unroll
            for (int e = 0; e < 8; ++e) {
                int idx = (e << 10) | tid;
                plo[b][idx] = (unsigned int)v[e];
                phi[b][idx] = (unsigned int)(v[e] >> 32);
            }
            __syncthreads();
            const int q = tid ^ c;
            const bool keep_min = (up == ((tid & c) == 0));
            #pragma unroll
            for (int e = 0; e < 8; ++e) {
                int idx = (e << 10) | q;
                unsigned long long w =
                    ((unsigned long long)phi[b][idx] << 32) | (unsigned long long)plo[b][idx];
                bool less = v[e] < w;
                v[e] = (less == keep_min) ? v[e] : w;
            }
            b ^= 1;
        }
        REG3(up)   // j = 4, 2, 1 in registers
    }

    // publish sorted order for a balanced strided decode
    #pragma unroll
    for (int e = 0; e < 8; ++e) {
        int idx = (e << 10) | tid;
        plo[b][idx] = (unsigned int)v[e];
        phi[b][idx] = (unsigned int)(v[e] >> 32);
    }
    __syncthreads();

    // decode boxes for the top-6000 (reference float32 op order, no contraction)
    for (int r = tid; r < PRE_N; r += 1024) {
        int idx = ((r & 7) << 10) | (r >> 3);
        unsigned int bidx = plo[b][idx];
        unsigned int sbits = ~phi[b][idx];
        float score = __uint_as_float(sbits);
        float a0 = anchors[(size_t)bidx * 4 + 0];
        float a1 = anchors[(size_t)bidx * 4 + 1];
        float a2 = anchors[(size_t)bidx * 4 + 2];
        float a3 = anchors[(size_t)bidx * 4 + 3];
        const float* dd = deltas + ((size_t)img * A + bidx) * 4;
        float d0 = dd[0] * 0.1f;
        float d1 = dd[1] * 0.1f;
        float d2 = dd[2] * 0.2f;
        float d3 = dd[3] * 0.2f;
        float anc_w = a3 - a1;
        float anc_h = a2 - a0;
        float anc_cx = a1 + 0.5f * anc_w;
        float anc_cy = a0 + 0.5f * anc_h;
        float bb_w = expf(d3) * anc_w;
        float bb_h = expf(d2) * anc_h;
        float bb_cx = d1 * anc_w + anc_cx;
        float bb_cy = d0 * anc_h + anc_cy;
        float y1 = bb_cy - 0.5f * bb_h;
        float x1 = bb_cx - 0.5f * bb_w;
        float y2 = bb_h + y1;
        float x2 = bb_w + x1;
        float* ob = pre_boxes + ((size_t)img * PRE_N + r) * 4;
        ob[0] = y1; ob[1] = x1; ob[2] = y2; ob[3] = x2;
        pre_scores[(size_t)img * PRE_N + r] = score;
    }
}

// ---------------- stage 3: chunked greedy NMS ----------------
// Scores are sorted desc with top_k tie order, so greedy NMS == scan boxes in
// index order, keep box j iff no previously-KEPT box suppresses it. Process in
// 94 chunks of 64:
//   phase E (all 8 waves): chunk boxes vs kept list (LDS), round-robin k=grp+8t,
//            early-break; one ballot+atomicAnd per wave into a 64-bit alive mask.
//   phase S (wave 0, no block barriers): resolve within-chunk order serially via
//            ffsll + shfl pivot broadcast + wave-wide IoU ballot.
// Suppression test = multiply prescreen with +-1e-6 decisive margins; exact
// reference division only in the borderline window -> bit-identical decisions
// to `inter/den > 0.7f` with reference float op order.
__global__ void __launch_bounds__(NMS_BLOCK)
nms_kernel(const float* __restrict__ pre_boxes,
           const float* __restrict__ pre_scores,
           float* __restrict__ out_boxes,    // [B][300][4] (pre-zeroed)
           float* __restrict__ out_scores) { // [B][300]
    const int img = blockIdx.x;
    const int tid = threadIdx.x;
    const int lane = tid & 63;
    const int grp = tid >> 6;                 // 0..7
    const float4* bb4 = (const float4*)(pre_boxes + (size_t)img * PRE_N * 4);

    __shared__ float4 kept[POST_N];           // kept boxes (in keep order)
    __shared__ float  kept_area[POST_N];
    __shared__ int    kept_idx[POST_N];       // global index into pre_* arrays
    __shared__ float4 chunkbox[64];
    __shared__ unsigned long long chunk_alive;
    __shared__ int kept_cnt;

    if (tid == 0) kept_cnt = 0;

    const int NCH = (PRE_N + 63) >> 6;        // 94 (last chunk: 48 valid)

    // prefetch chunk 0 (grp 0 owns staging)
    float4 nb = make_float4(0.f, 0.f, 0.f, 0.f);
    if (grp == 0) nb = bb4[lane];             // chunk 0 fully valid (64 <= 6000)

    for (int c = 0; c < NCH; ++c) {
        const int base = c << 6;
        if (grp == 0) chunkbox[lane] = nb;
        if (tid == 0) {
            int rem = PRE_N - base;
            chunk_alive = (rem >= 64) ? ~0ull : ((1ull << rem) - 1ull);
        }
        __syncthreads();

        // issue next-chunk prefetch early; latency hides under phases E+S
        if (grp == 0 && c + 1 < NCH) {
            int j = base + 64 + lane;
            nb = (j < PRE_N) ? bb4[j] : make_float4(0.f, 0.f, 0.f, 0.f);
        }

        const int K = kept_cnt;
        float4 mb = chunkbox[lane];
        float marea = (mb.z - mb.x) * (mb.w - mb.y);

        // ---- phase E: external suppression vs previously-kept boxes ----
        bool sup = false;
        for (int k = grp; k < K; k += 8) {
            float4 pb = kept[k];              // LDS broadcast (uniform addr per wave)
            float pa = kept_area[k];
            float iy1 = fmaxf(pb.x, mb.x);
            float ix1 = fmaxf(pb.y, mb.y);
            float iy2 = fminf(pb.z, mb.z);
            float ix2 = fminf(pb.w, mb.w);
            float ih = iy2 - iy1; ih = ih > 0.f ? ih : 0.f;
            float iw = ix2 - ix1; iw = iw > 0.f ? iw : 0.f;
            float inter = ih * iw;
            float den = marea + pa - inter + 1e-9f;  // ref order: ((areas+b_area)-inter)+eps
            float hi = 0.7000007f * den;
            float lo = 0.6999993f * den;
            bool s = inter > hi;
            if (inter >= lo && inter <= hi)
                s = (inter / den) > NMS_IOU_T;
            if (s) { sup = true; break; }
        }
        unsigned long long bal = __ballot(sup ? 1 : 0);
        if (lane == 0 && bal) atomicAnd(&chunk_alive, ~bal);
        __syncthreads();

        // ---- phase S: serial within-chunk resolution (wave 0 only) ----
        if (grp == 0) {
            unsigned long long m = chunk_alive;
            int kc = K;
            while (m && kc < POST_N) {
                int i = __ffsll(m) - 1;
                float py1 = __shfl(mb.x, i);
                float px1 = __shfl(mb.y, i);
                float py2 = __shfl(mb.z, i);
                float px2 = __shfl(mb.w, i);
                float pa  = __shfl(marea, i);
                if (lane == i) {
                    kept[kc] = mb;
                    kept_area[kc] = marea;
                    kept_idx[kc] = base + i;
                }
                float iy1 = fmaxf(py1, mb.x);
                float ix1 = fmaxf(px1, mb.y);
                float iy2 = fminf(py2, mb.z);
                float ix2 = fminf(px2, mb.w);
                float ih = iy2 - iy1; ih = ih > 0.f ? ih : 0.f;
                float iw = ix2 - ix1; iw = iw > 0.f ? iw : 0.f;
                float inter = ih * iw;
                float den = marea + pa - inter + 1e-9f;
                float hi = 0.7000007f * den;
                float lo = 0.6999993f * den;
                bool s = inter > hi;
                if (inter >= lo && inter <= hi)
                    s = (inter / den) > NMS_IOU_T;
                unsigned long long sb = __ballot(s ? 1 : 0);
                m &= ~sb;
                m &= ~(1ull << i);            // pivot resolved (self-IoU ~= 1 anyway)
                ++kc;
            }
            if (lane == 0) kept_cnt = kc;
        }
        __syncthreads();
        if (kept_cnt >= POST_N) break;        // uniform
    }

    // ---- write outputs (rest of the pre-zeroed buffer stays zero) ----
    const int kc = kept_cnt;
    for (int r = tid; r < kc; r += NMS_BLOCK) {
        float4 bx = kept[r];
        float* ob = out_boxes + ((size_t)img * POST_N + r) * 4;
        ob[0] = bx.x; ob[1] = bx.y; ob[2] = bx.z; ob[3] = bx.w;
        out_scores[(size_t)img * POST_N + r] =
            pre_scores[(size_t)img * PRE_N + kept_idx[r]];
    }
}

extern "C" void kernel_launch(void* const* d_in, const int* in_sizes, int n_in,
                              void* d_out, int out_size, void* d_ws, size_t ws_size,
                              hipStream_t stream) {
    const float* deltas  = (const float*)d_in[0];  // (B, A, 4)
    const float* labels  = (const float*)d_in[1];  // (B, FH, FW, 9)
    const float* anchors = (const float*)d_in[2];  // (A, 4)
    float* out = (float*)d_out;

    const int A = in_sizes[2] / 4;                 // 147456
    const int B = in_sizes[0] / (A * 4);           // 32
    const int ngroups = in_sizes[1] / KCLS;        // B*FH*FW

    // workspace layout
    float* scores     = (float*)d_ws;                                // B*A
    float* pre_boxes  = scores + (size_t)B * A;                      // B*6000*4
    float* pre_scores = pre_boxes + (size_t)B * PRE_N * 4;           // B*6000
    unsigned int* hist  = (unsigned int*)(pre_scores + (size_t)B * PRE_N);  // 3*B*2048
    unsigned int* state = hist + (size_t)3 * B * 2048;               // B*2

    float* out_boxes  = out;                        // B*300*4
    float* out_scores = out + (size_t)B * POST_N * 4;

    hipMemsetAsync(d_out, 0, (size_t)out_size * sizeof(float), stream);
    hipMemsetAsync(hist, 0, (size_t)3 * B * 2048 * sizeof(unsigned int), stream);

    softmax_kernel<<<(ngroups + 255) / 256, 256, 0, stream>>>(labels, scores, ngroups);

    dim3 hgrid(CHUNKS_PER_IMG, B);
    // pass 1: bits [31:21]
    hist_kernel<<<hgrid, HIST_BLOCK, 0, stream>>>(scores, hist + (size_t)0 * B * 2048, state, A, 21, 2048, 0x00000000u);
    pick_kernel<<<B, PICK_BLOCK, 0, stream>>>(hist + (size_t)0 * B * 2048, state, 21, 2048, 1);
    // pass 2: bits [20:10]
    hist_kernel<<<hgrid, HIST_BLOCK, 0, stream>>>(scores, hist + (size_t)1 * B * 2048, state, A, 10, 2048, 0xFFE00000u);
    pick_kernel<<<B, PICK_BLOCK, 0, stream>>>(hist + (size_t)1 * B * 2048, state, 10, 2048, 0);
    // pass 3: bits [9:0]
    hist_kernel<<<hgrid, HIST_BLOCK, 0, stream>>>(scores, hist + (size_t)2 * B * 2048, state, A, 0, 1024, 0xFFFFFC00u);
    pick_kernel<<<B, PICK_BLOCK, 0, stream>>>(hist + (size_t)2 * B * 2048, state, 0, 1024, 0);

    topk_sort_kernel<<<B, 1024, 0, stream>>>(
        scores, deltas, anchors, state, pre_boxes, pre_scores, A);

    nms_kernel<<<B, NMS_BLOCK, 0, stream>>>(pre_boxes, pre_scores, out_boxes, out_scores);
}

// Round 3
// 304.155 us; speedup vs baseline: 2.5951x; 1.2060x over previous
//
#include <hip/hip_runtime.h>
#include <cstdint>
#include <cstddef>

// Match numpy/XLA float32 semantics: no FMA contraction anywhere.
#pragma clang fp contract(off)

#define KCLS 9
#define PRE_N 6000
#define POST_N 300
#define NMS_IOU_T 0.7f
#define HIST_BLOCK 256
#define CHUNKS_PER_IMG 32
#define NMS_BLOCK 512
#define PICK_BLOCK 256
#define NSEG 4
#define SEG_CAP 4096

// ---------------- stage 1: softmax over K=9, fused with radix pass-1 histogram ----------------
__global__ void __launch_bounds__(256)
softmax_hist_kernel(const float* __restrict__ labels,
                    float* __restrict__ scores,
                    unsigned int* __restrict__ ghist,   // [B][2048] (pass-1 slot)
                    int ngroups, int gpi) {             // gpi = groups per image (16384)
    __shared__ unsigned int h[2048];
    const int tid = threadIdx.x;
    for (int i = tid; i < 2048; i += 256) h[i] = 0u;
    __syncthreads();
    const int g = blockIdx.x * 256 + tid;
    if (g < ngroups) {
        const float* x = labels + (size_t)g * KCLS;
        float v[KCLS];
        float m = -1e30f;
        #pragma unroll
        for (int k = 0; k < KCLS; ++k) { v[k] = x[k]; m = fmaxf(m, v[k]); }
        float e[KCLS];
        float s = 0.f;
        #pragma unroll
        for (int k = 0; k < KCLS; ++k) { e[k] = expf(v[k] - m); s += e[k]; }
        float* o = scores + (size_t)g * KCLS;
        #pragma unroll
        for (int k = 0; k < KCLS; ++k) {
            float r = e[k] / s;
            o[k] = r;
            atomicAdd(&h[(__float_as_uint(r) >> 21) & 2047u], 1u);
        }
    }
    __syncthreads();
    const int img0 = (blockIdx.x * 256) / gpi;   // gpi % 256 == 0 -> block spans one image
    unsigned int* gh = ghist + (size_t)img0 * 2048;
    for (int i = tid; i < 2048; i += 256) {
        unsigned int c = h[i];
        if (c) atomicAdd(&gh[i], c);
    }
}

// ---------------- stage 2a: per-pass radix histogram (passes 2,3) ----------------
__global__ void hist_kernel(const float* __restrict__ scores,
                            unsigned int* __restrict__ ghist,        // [B][2048]
                            const unsigned int* __restrict__ state,  // [B][2] {prefix,krem}
                            int A, int shift, int bins, unsigned int pmask) {
    __shared__ unsigned int h[2048];
    const int img = blockIdx.y;
    const int chunk = blockIdx.x;
    const int tid = threadIdx.x;
    for (int i = tid; i < bins; i += HIST_BLOCK) h[i] = 0u;
    __syncthreads();
    unsigned int prefix = pmask ? (state[img * 2 + 0] & pmask) : 0u;
    const int per = A / CHUNKS_PER_IMG;
    const float* sc = scores + (size_t)img * A + (size_t)chunk * per;
    for (int i = tid; i < per; i += HIST_BLOCK) {
        unsigned int v = __float_as_uint(sc[i]);   // scores > 0: uint order == float order
        if ((v & pmask) == prefix)
            atomicAdd(&h[(v >> shift) & (unsigned)(bins - 1)], 1u);
    }
    __syncthreads();
    unsigned int* gh = ghist + (size_t)img * 2048;
    for (int i = tid; i < bins; i += HIST_BLOCK) {
        unsigned int c = h[i];
        if (c) atomicAdd(&gh[i], c);
    }
}

// ---------------- stage 2b: pick target bin (parallel suffix scan) ----------------
__global__ void __launch_bounds__(PICK_BLOCK)
pick_kernel(const unsigned int* __restrict__ ghist,
            unsigned int* __restrict__ state,
            int shift, int bins, int first_pass) {
    const int img = blockIdx.x;
    const int t = threadIdx.x;
    const unsigned int* gh = ghist + (size_t)img * 2048;
    __shared__ unsigned int cnt[2048];
    __shared__ unsigned int ssum[PICK_BLOCK];
    const int per = bins / PICK_BLOCK;   // 8 or 4
    unsigned int my = 0;
    for (int i = 0; i < per; ++i) {
        unsigned int c = gh[t * per + i];
        cnt[t * per + i] = c;
        my += c;
    }
    ssum[t] = my;
    __syncthreads();
    // inclusive suffix scan: ssum[t] = sum_{u >= t} chunk_sum[u]
    for (int d = 1; d < PICK_BLOCK; d <<= 1) {
        unsigned int v = (t + d < PICK_BLOCK) ? ssum[t + d] : 0u;
        __syncthreads();
        ssum[t] += v;
        __syncthreads();
    }
    unsigned int prefix = first_pass ? 0u : state[img * 2 + 0];
    unsigned int krem = first_pass ? (unsigned)PRE_N : state[img * 2 + 1];
    unsigned int above = ssum[t] - my;   // strictly above my chunk
    if (above < krem && ssum[t] >= krem) {   // unique thread
        unsigned int cum = above;
        for (int b = per - 1; b >= 0; --b) {
            unsigned int c = cnt[t * per + b];
            if (cum + c >= krem) {
                state[img * 2 + 0] = prefix | ((unsigned int)(t * per + b) << shift);
                state[img * 2 + 1] = krem - cum;
                break;
            }
            cum += c;
        }
    }
}

// ---------------- stage 2c: per-segment compact + register-blocked bitonic sort ----------------
// grid (NSEG, B): each block owns the indices i with (i>>6)%NSEG == seg of one
// image (round-robin 64-groups -> balanced segments). Compacts score>=T into
// LDS, sorts its ~1500 candidates (P2 = next_pow2 >= 512) with the verified
// register-blocked bitonic (8 elems/thread, NT = P2/8 active threads,
// double-buffered planes -> 1 barrier/stage), writes sorted chunk to global.
// Keys (~score_bits, index) are unique -> total order well-defined.
#define CE(a, b, u) { if ((v[a] > v[b]) == (u)) { unsigned long long t_ = v[a]; v[a] = v[b]; v[b] = t_; } }
#define REG3(u) { CE(0,4,u) CE(1,5,u) CE(2,6,u) CE(3,7,u) \
                  CE(0,2,u) CE(1,3,u) CE(4,6,u) CE(5,7,u) \
                  CE(0,1,u) CE(2,3,u) CE(4,5,u) CE(6,7,u) }

__global__ void __launch_bounds__(512)
compact_sort_kernel(const float* __restrict__ scores,
                    const unsigned int* __restrict__ state,
                    unsigned long long* __restrict__ pool,   // [B][NSEG][SEG_CAP]
                    unsigned int* __restrict__ counts,       // [B][NSEG]
                    int A) {
    __shared__ unsigned long long lin[SEG_CAP];   // 32 KB
    __shared__ unsigned int plo[2][SEG_CAP];      // 32 KB
    __shared__ unsigned int phi[2][SEG_CAP];      // 32 KB
    __shared__ unsigned int cnt;
    const int img = blockIdx.y;
    const int seg = blockIdx.x;
    const int tid = threadIdx.x;
    const int lane = tid & 63;
    const int w = tid >> 6;                       // wave 0..7
    const float* sc = scores + (size_t)img * A;
    const unsigned int T = state[img * 2 + 0];    // exact bits of 6000th-largest score

    if (tid == 0) cnt = 0u;
    for (int i = tid; i < SEG_CAP; i += 512) lin[i] = ~0ull;  // pad keys = max
    __syncthreads();

    // compact: groups g == seg (mod NSEG), wave-aggregated LDS push
    const int ngr = A >> 6;                       // 64-element groups (2304)
    const int nj = ngr / NSEG;                    // groups per segment (576)
    for (int j = w; j < nj; j += 8) {
        int g = seg + j * NSEG;
        int i = (g << 6) + lane;
        unsigned int sv = __float_as_uint(sc[i]); // scores > 0: uint order == float order
        bool push = (sv >= T);
        unsigned long long bal = __ballot(push ? 1 : 0);
        if (push) {
            int leader = __ffsll(bal) - 1;
            int rank = __popcll(bal & ((1ull << lane) - 1ull));
            unsigned int base = 0;
            if (lane == leader) base = atomicAdd(&cnt, (unsigned int)__popcll(bal));
            base = (unsigned int)__shfl((int)base, leader);
            unsigned int pos = base + (unsigned int)rank;
            if (pos < SEG_CAP)
                lin[pos] = (((unsigned long long)(~sv)) << 32) | (unsigned long long)(unsigned int)i;
        }
    }
    __syncthreads();

    int n = (int)cnt; if (n > SEG_CAP) n = SEG_CAP;
    int P2 = 512; while (P2 < n) P2 <<= 1;        // 512..4096 (block-uniform)
    const int NT = P2 >> 3;                       // active threads
    const int t = tid;
    const bool act = (t < NT);

    unsigned long long v[8];
    if (act) {
        #pragma unroll
        for (int e = 0; e < 8; ++e) v[e] = lin[(t << 3) + e];
        // k=2,4,8 (in-register)
        CE(0,1,true) CE(2,3,false) CE(4,5,true) CE(6,7,false)
        CE(0,2,true) CE(1,3,true) CE(4,6,false) CE(5,7,false)
        CE(0,1,true) CE(2,3,true) CE(4,5,false) CE(6,7,false)
        bool u8 = ((t & 1) == 0);
        REG3(u8)
    }
    int b = 0;
    for (int k = 16; k <= P2; k <<= 1) {
        const bool up = (((t << 3) & k) == 0);
        for (int j = k >> 1; j >= 8; j >>= 1) {
            const int c = j >> 3;
            if (act) {
                #pragma unroll
                for (int e = 0; e < 8; ++e) {
                    int idx = e * NT + t;
                    plo[b][idx] = (unsigned int)v[e];
                    phi[b][idx] = (unsigned int)(v[e] >> 32);
                }
            }
            __syncthreads();
            if (act) {
                const int q = t ^ c;
                const bool keep_min = (up == ((t & c) == 0));
                #pragma unroll
                for (int e = 0; e < 8; ++e) {
                    int idx = e * NT + q;
                    unsigned long long wv = ((unsigned long long)phi[b][idx] << 32)
                                          | (unsigned long long)plo[b][idx];
                    bool less = v[e] < wv;
                    v[e] = (less == keep_min) ? v[e] : wv;
                }
            }
            b ^= 1;
        }
        if (act) { REG3(up) }
    }

    unsigned long long* gp = pool + ((size_t)img * NSEG + seg) * SEG_CAP;
    if (act) {
        #pragma unroll
        for (int e = 0; e < 8; ++e) {
            int r = (t << 3) + e;
            if (r < n) gp[r] = v[e];
        }
    }
    if (tid == 0) counts[img * NSEG + seg] = (unsigned int)n;
}

// ---------------- stage 2d: rank (merge by binary search) + decode ----------------
// grid (NSEG, B): block ranks its own sorted segment against the other 3 via
// lower_bound (keys unique -> exact rank = own_pos + sum of strict-less counts),
// then decodes elements with rank < 6000 directly into pre_boxes[rank].
__global__ void __launch_bounds__(256)
rank_decode_kernel(const unsigned long long* __restrict__ pool,
                   const unsigned int* __restrict__ counts,
                   const float* __restrict__ deltas,   // [B][A][4]
                   const float* __restrict__ anchors,  // [A][4]
                   float* __restrict__ pre_boxes,      // [B][6000][4]
                   float* __restrict__ pre_scores,     // [B][6000]
                   int A) {
    __shared__ unsigned long long arr[2 * SEG_CAP];   // 64 KB (total <= 8192 fast path)
    const int img = blockIdx.y;
    const int seg = blockIdx.x;
    const int tid = threadIdx.x;

    int c[NSEG], off[NSEG + 1];
    const unsigned long long* gp[NSEG];
    off[0] = 0;
    #pragma unroll
    for (int s = 0; s < NSEG; ++s) {
        int cs = (int)counts[img * NSEG + s];
        if (cs > SEG_CAP) cs = SEG_CAP;
        c[s] = cs;
        off[s + 1] = off[s] + cs;
        gp[s] = pool + ((size_t)img * NSEG + s) * SEG_CAP;
    }
    const int total = off[NSEG];
    const bool inlds = (total <= 2 * SEG_CAP);
    if (inlds) {
        #pragma unroll
        for (int s = 0; s < NSEG; ++s)
            for (int i = tid; i < c[s]; i += 256) arr[off[s] + i] = gp[s][i];
    }
    __syncthreads();

    const int m = c[seg];
    for (int i = tid; i < m; i += 256) {
        unsigned long long key = inlds ? arr[off[seg] + i] : gp[seg][i];
        int pos = i;
        #pragma unroll
        for (int s = 0; s < NSEG; ++s) {
            if (s == seg) continue;
            const unsigned long long* base = inlds ? (arr + off[s]) : gp[s];
            int lo = 0, hi = c[s];
            while (lo < hi) {
                int mid = (lo + hi) >> 1;
                if (base[mid] < key) lo = mid + 1; else hi = mid;
            }
            pos += lo;
        }
        if (pos < PRE_N) {
            unsigned int bidx = (unsigned int)(key & 0xFFFFFFFFull);
            unsigned int sbits = ~((unsigned int)(key >> 32));
            float score = __uint_as_float(sbits);
            float a0 = anchors[(size_t)bidx * 4 + 0];
            float a1 = anchors[(size_t)bidx * 4 + 1];
            float a2 = anchors[(size_t)bidx * 4 + 2];
            float a3 = anchors[(size_t)bidx * 4 + 3];
            const float* dd = deltas + ((size_t)img * A + bidx) * 4;
            float d0 = dd[0] * 0.1f;
            float d1 = dd[1] * 0.1f;
            float d2 = dd[2] * 0.2f;
            float d3 = dd[3] * 0.2f;
            float anc_w = a3 - a1;
            float anc_h = a2 - a0;
            float anc_cx = a1 + 0.5f * anc_w;
            float anc_cy = a0 + 0.5f * anc_h;
            float bb_w = expf(d3) * anc_w;
            float bb_h = expf(d2) * anc_h;
            float bb_cx = d1 * anc_w + anc_cx;
            float bb_cy = d0 * anc_h + anc_cy;
            float y1 = bb_cy - 0.5f * bb_h;
            float x1 = bb_cx - 0.5f * bb_w;
            float y2 = bb_h + y1;
            float x2 = bb_w + x1;
            float* ob = pre_boxes + ((size_t)img * PRE_N + pos) * 4;
            ob[0] = y1; ob[1] = x1; ob[2] = y2; ob[3] = x2;
            pre_scores[(size_t)img * PRE_N + pos] = score;
        }
    }
}

// ---------------- stage 3: chunked greedy NMS ----------------
// Scores sorted desc with top_k tie order => greedy NMS == scan in index order,
// keep box j iff no previously-KEPT box suppresses it. 94 chunks of 64:
//   phase E (8 waves): chunk boxes vs kept list (LDS), early-break;
//   phase S (wave 0): serial within-chunk resolution via ffsll + shfl + ballot.
// Multiply prescreen with +-1e-6 decisive margins; exact reference division in
// the borderline window -> bit-identical decisions to `inter/den > 0.7f`.
__global__ void __launch_bounds__(NMS_BLOCK)
nms_kernel(const float* __restrict__ pre_boxes,
           const float* __restrict__ pre_scores,
           float* __restrict__ out_boxes,    // [B][300][4] (pre-zeroed)
           float* __restrict__ out_scores) { // [B][300]
    const int img = blockIdx.x;
    const int tid = threadIdx.x;
    const int lane = tid & 63;
    const int grp = tid >> 6;                 // 0..7
    const float4* bb4 = (const float4*)(pre_boxes + (size_t)img * PRE_N * 4);

    __shared__ float4 kept[POST_N];           // kept boxes (in keep order)
    __shared__ float  kept_area[POST_N];
    __shared__ int    kept_idx[POST_N];       // global index into pre_* arrays
    __shared__ float4 chunkbox[64];
    __shared__ unsigned long long chunk_alive;
    __shared__ int kept_cnt;

    if (tid == 0) kept_cnt = 0;

    const int NCH = (PRE_N + 63) >> 6;        // 94 (last chunk: 48 valid)

    // prefetch chunk 0 (grp 0 owns staging)
    float4 nb = make_float4(0.f, 0.f, 0.f, 0.f);
    if (grp == 0) nb = bb4[lane];             // chunk 0 fully valid (64 <= 6000)

    for (int c = 0; c < NCH; ++c) {
        const int base = c << 6;
        if (grp == 0) chunkbox[lane] = nb;
        if (tid == 0) {
            int rem = PRE_N - base;
            chunk_alive = (rem >= 64) ? ~0ull : ((1ull << rem) - 1ull);
        }
        __syncthreads();

        // issue next-chunk prefetch early; latency hides under phases E+S
        if (grp == 0 && c + 1 < NCH) {
            int j = base + 64 + lane;
            nb = (j < PRE_N) ? bb4[j] : make_float4(0.f, 0.f, 0.f, 0.f);
        }

        const int K = kept_cnt;
        float4 mb = chunkbox[lane];
        float marea = (mb.z - mb.x) * (mb.w - mb.y);

        // ---- phase E: external suppression vs previously-kept boxes ----
        bool sup = false;
        for (int k = grp; k < K; k += 8) {
            float4 pb = kept[k];              // LDS broadcast (uniform addr per wave)
            float pa = kept_area[k];
            float iy1 = fmaxf(pb.x, mb.x);
            float ix1 = fmaxf(pb.y, mb.y);
            float iy2 = fminf(pb.z, mb.z);
            float ix2 = fminf(pb.w, mb.w);
            float ih = iy2 - iy1; ih = ih > 0.f ? ih : 0.f;
            float iw = ix2 - ix1; iw = iw > 0.f ? iw : 0.f;
            float inter = ih * iw;
            float den = marea + pa - inter + 1e-9f;  // ref order: ((areas+b_area)-inter)+eps
            float hi = 0.7000007f * den;
            float lo = 0.6999993f * den;
            bool s = inter > hi;
            if (inter >= lo && inter <= hi)
                s = (inter / den) > NMS_IOU_T;
            if (s) { sup = true; break; }
        }
        unsigned long long bal = __ballot(sup ? 1 : 0);
        if (lane == 0 && bal) atomicAnd(&chunk_alive, ~bal);
        __syncthreads();

        // ---- phase S: serial within-chunk resolution (wave 0 only) ----
        if (grp == 0) {
            unsigned long long m = chunk_alive;
            int kc = K;
            while (m && kc < POST_N) {
                int i = __ffsll(m) - 1;
                float py1 = __shfl(mb.x, i);
                float px1 = __shfl(mb.y, i);
                float py2 = __shfl(mb.z, i);
                float px2 = __shfl(mb.w, i);
                float pa  = __shfl(marea, i);
                if (lane == i) {
                    kept[kc] = mb;
                    kept_area[kc] = marea;
                    kept_idx[kc] = base + i;
                }
                float iy1 = fmaxf(py1, mb.x);
                float ix1 = fmaxf(px1, mb.y);
                float iy2 = fminf(py2, mb.z);
                float ix2 = fminf(px2, mb.w);
                float ih = iy2 - iy1; ih = ih > 0.f ? ih : 0.f;
                float iw = ix2 - ix1; iw = iw > 0.f ? iw : 0.f;
                float inter = ih * iw;
                float den = marea + pa - inter + 1e-9f;
                float hi = 0.7000007f * den;
                float lo = 0.6999993f * den;
                bool s = inter > hi;
                if (inter >= lo && inter <= hi)
                    s = (inter / den) > NMS_IOU_T;
                unsigned long long sb = __ballot(s ? 1 : 0);
                m &= ~sb;
                m &= ~(1ull << i);            // pivot resolved (self-IoU ~= 1 anyway)
                ++kc;
            }
            if (lane == 0) kept_cnt = kc;
        }
        __syncthreads();
        if (kept_cnt >= POST_N) break;        // uniform
    }

    // ---- write outputs (rest of the pre-zeroed buffer stays zero) ----
    const int kc = kept_cnt;
    for (int r = tid; r < kc; r += NMS_BLOCK) {
        float4 bx = kept[r];
        float* ob = out_boxes + ((size_t)img * POST_N + r) * 4;
        ob[0] = bx.x; ob[1] = bx.y; ob[2] = bx.z; ob[3] = bx.w;
        out_scores[(size_t)img * POST_N + r] =
            pre_scores[(size_t)img * PRE_N + kept_idx[r]];
    }
}

extern "C" void kernel_launch(void* const* d_in, const int* in_sizes, int n_in,
                              void* d_out, int out_size, void* d_ws, size_t ws_size,
                              hipStream_t stream) {
    const float* deltas  = (const float*)d_in[0];  // (B, A, 4)
    const float* labels  = (const float*)d_in[1];  // (B, FH, FW, 9)
    const float* anchors = (const float*)d_in[2];  // (A, 4)
    float* out = (float*)d_out;

    const int A = in_sizes[2] / 4;                 // 147456
    const int B = in_sizes[0] / (A * 4);           // 32
    const int ngroups = in_sizes[1] / KCLS;        // B*FH*FW
    const int gpi = ngroups / B;                   // 16384

    // workspace layout
    float* scores     = (float*)d_ws;                                // B*A
    float* pre_boxes  = scores + (size_t)B * A;                      // B*6000*4
    float* pre_scores = pre_boxes + (size_t)B * PRE_N * 4;           // B*6000
    unsigned int* hist  = (unsigned int*)(pre_scores + (size_t)B * PRE_N);  // 3*B*2048
    unsigned int* state = hist + (size_t)3 * B * 2048;               // B*2
    unsigned long long* pool = (unsigned long long*)(state + (size_t)B * 2); // B*NSEG*SEG_CAP u64
    unsigned int* counts = (unsigned int*)(pool + (size_t)B * NSEG * SEG_CAP); // B*NSEG

    float* out_boxes  = out;                        // B*300*4
    float* out_scores = out + (size_t)B * POST_N * 4;

    hipMemsetAsync(d_out, 0, (size_t)out_size * sizeof(float), stream);
    hipMemsetAsync(hist, 0, (size_t)3 * B * 2048 * sizeof(unsigned int), stream);

    // fused softmax + radix pass-1 histogram (bits [31:21])
    softmax_hist_kernel<<<(ngroups + 255) / 256, 256, 0, stream>>>(
        labels, scores, hist + (size_t)0 * B * 2048, ngroups, gpi);
    pick_kernel<<<B, PICK_BLOCK, 0, stream>>>(hist + (size_t)0 * B * 2048, state, 21, 2048, 1);

    dim3 hgrid(CHUNKS_PER_IMG, B);
    // pass 2: bits [20:10]
    hist_kernel<<<hgrid, HIST_BLOCK, 0, stream>>>(scores, hist + (size_t)1 * B * 2048, state, A, 10, 2048, 0xFFE00000u);
    pick_kernel<<<B, PICK_BLOCK, 0, stream>>>(hist + (size_t)1 * B * 2048, state, 10, 2048, 0);
    // pass 3: bits [9:0]
    hist_kernel<<<hgrid, HIST_BLOCK, 0, stream>>>(scores, hist + (size_t)2 * B * 2048, state, A, 0, 1024, 0xFFFFFC00u);
    pick_kernel<<<B, PICK_BLOCK, 0, stream>>>(hist + (size_t)2 * B * 2048, state, 0, 1024, 0);

    dim3 sgrid(NSEG, B);
    compact_sort_kernel<<<sgrid, 512, 0, stream>>>(scores, state, pool, counts, A);
    rank_decode_kernel<<<sgrid, 256, 0, stream>>>(pool, counts, deltas, anchors,
                                                  pre_boxes, pre_scores, A);

    nms_kernel<<<B, NMS_BLOCK, 0, stream>>>(pre_boxes, pre_scores, out_boxes, out_scores);
}

// Round 4
// 289.476 us; speedup vs baseline: 2.7267x; 1.0507x over previous
//
#include <hip/hip_runtime.h>
#include <cstdint>
#include <cstddef>

// Match numpy/XLA float32 semantics: no FMA contraction anywhere.
#pragma clang fp contract(off)

#define KCLS 9
#define PRE_N 6000
#define POST_N 300
#define NMS_IOU_T 0.7f
#define HIST_BLOCK 256
#define CHUNKS_PER_IMG 32
#define NMS_BLOCK 512
#define PICK_BLOCK 256
#define NSEG 4
#define SEG_CAP 4096

// Decisive-margin suppression test: multiply prescreen with +-1e-6 margins,
// exact reference division only in the borderline window -> bit-identical
// decisions to `inter/den > 0.7f` with reference float op order.
#define SUPP(pb, pa, mbx, mar, out) \
    bool out; { \
        float iy1_ = fmaxf((pb).x, (mbx).x); \
        float ix1_ = fmaxf((pb).y, (mbx).y); \
        float iy2_ = fminf((pb).z, (mbx).z); \
        float ix2_ = fminf((pb).w, (mbx).w); \
        float ih_ = iy2_ - iy1_; ih_ = ih_ > 0.f ? ih_ : 0.f; \
        float iw_ = ix2_ - ix1_; iw_ = iw_ > 0.f ? iw_ : 0.f; \
        float inter_ = ih_ * iw_; \
        float den_ = (mar) + (pa) - inter_ + 1e-9f; \
        float hi_ = 0.7000007f * den_; \
        float lo_ = 0.6999993f * den_; \
        out = inter_ > hi_; \
        if (inter_ >= lo_ && inter_ <= hi_) out = (inter_ / den_) > NMS_IOU_T; \
    }

// ---------------- stage 1: softmax over K=9, fused with radix pass-1 histogram ----------------
__global__ void __launch_bounds__(256)
softmax_hist_kernel(const float* __restrict__ labels,
                    float* __restrict__ scores,
                    unsigned int* __restrict__ ghist,   // [B][2048] (pass-1 slot)
                    int ngroups, int gpi) {             // gpi = groups per image (16384)
    __shared__ unsigned int h[2048];
    const int tid = threadIdx.x;
    for (int i = tid; i < 2048; i += 256) h[i] = 0u;
    __syncthreads();
    const int g = blockIdx.x * 256 + tid;
    if (g < ngroups) {
        const float* x = labels + (size_t)g * KCLS;
        float v[KCLS];
        float m = -1e30f;
        #pragma unroll
        for (int k = 0; k < KCLS; ++k) { v[k] = x[k]; m = fmaxf(m, v[k]); }
        float e[KCLS];
        float s = 0.f;
        #pragma unroll
        for (int k = 0; k < KCLS; ++k) { e[k] = expf(v[k] - m); s += e[k]; }
        float* o = scores + (size_t)g * KCLS;
        #pragma unroll
        for (int k = 0; k < KCLS; ++k) {
            float r = e[k] / s;
            o[k] = r;
            atomicAdd(&h[(__float_as_uint(r) >> 21) & 2047u], 1u);
        }
    }
    __syncthreads();
    const int img0 = (blockIdx.x * 256) / gpi;   // gpi % 256 == 0 -> block spans one image
    unsigned int* gh = ghist + (size_t)img0 * 2048;
    for (int i = tid; i < 2048; i += 256) {
        unsigned int c = h[i];
        if (c) atomicAdd(&gh[i], c);
    }
}

// ---------------- stage 2a: per-pass radix histogram (passes 2,3) ----------------
__global__ void hist_kernel(const float* __restrict__ scores,
                            unsigned int* __restrict__ ghist,        // [B][2048]
                            const unsigned int* __restrict__ state,  // [B][2] {prefix,krem}
                            int A, int shift, int bins, unsigned int pmask) {
    __shared__ unsigned int h[2048];
    const int img = blockIdx.y;
    const int chunk = blockIdx.x;
    const int tid = threadIdx.x;
    for (int i = tid; i < bins; i += HIST_BLOCK) h[i] = 0u;
    __syncthreads();
    unsigned int prefix = pmask ? (state[img * 2 + 0] & pmask) : 0u;
    const int per = A / CHUNKS_PER_IMG;
    const float* sc = scores + (size_t)img * A + (size_t)chunk * per;
    for (int i = tid; i < per; i += HIST_BLOCK) {
        unsigned int v = __float_as_uint(sc[i]);   // scores > 0: uint order == float order
        if ((v & pmask) == prefix)
            atomicAdd(&h[(v >> shift) & (unsigned)(bins - 1)], 1u);
    }
    __syncthreads();
    unsigned int* gh = ghist + (size_t)img * 2048;
    for (int i = tid; i < bins; i += HIST_BLOCK) {
        unsigned int c = h[i];
        if (c) atomicAdd(&gh[i], c);
    }
}

// ---------------- stage 2b: pick target bin (parallel suffix scan) ----------------
__global__ void __launch_bounds__(PICK_BLOCK)
pick_kernel(const unsigned int* __restrict__ ghist,
            unsigned int* __restrict__ state,
            int shift, int bins, int first_pass) {
    const int img = blockIdx.x;
    const int t = threadIdx.x;
    const unsigned int* gh = ghist + (size_t)img * 2048;
    __shared__ unsigned int cnt[2048];
    __shared__ unsigned int ssum[PICK_BLOCK];
    const int per = bins / PICK_BLOCK;   // 8 or 4
    unsigned int my = 0;
    for (int i = 0; i < per; ++i) {
        unsigned int c = gh[t * per + i];
        cnt[t * per + i] = c;
        my += c;
    }
    ssum[t] = my;
    __syncthreads();
    // inclusive suffix scan: ssum[t] = sum_{u >= t} chunk_sum[u]
    for (int d = 1; d < PICK_BLOCK; d <<= 1) {
        unsigned int v = (t + d < PICK_BLOCK) ? ssum[t + d] : 0u;
        __syncthreads();
        ssum[t] += v;
        __syncthreads();
    }
    unsigned int prefix = first_pass ? 0u : state[img * 2 + 0];
    unsigned int krem = first_pass ? (unsigned)PRE_N : state[img * 2 + 1];
    unsigned int above = ssum[t] - my;   // strictly above my chunk
    if (above < krem && ssum[t] >= krem) {   // unique thread
        unsigned int cum = above;
        for (int b = per - 1; b >= 0; --b) {
            unsigned int c = cnt[t * per + b];
            if (cum + c >= krem) {
                state[img * 2 + 0] = prefix | ((unsigned int)(t * per + b) << shift);
                state[img * 2 + 1] = krem - cum;
                break;
            }
            cum += c;
        }
    }
}

// ---------------- stage 2c: per-segment compact + register-blocked bitonic sort ----------------
#define CE(a, b, u) { if ((v[a] > v[b]) == (u)) { unsigned long long t_ = v[a]; v[a] = v[b]; v[b] = t_; } }
#define REG3(u) { CE(0,4,u) CE(1,5,u) CE(2,6,u) CE(3,7,u) \
                  CE(0,2,u) CE(1,3,u) CE(4,6,u) CE(5,7,u) \
                  CE(0,1,u) CE(2,3,u) CE(4,5,u) CE(6,7,u) }

__global__ void __launch_bounds__(512)
compact_sort_kernel(const float* __restrict__ scores,
                    const unsigned int* __restrict__ state,
                    unsigned long long* __restrict__ pool,   // [B][NSEG][SEG_CAP]
                    unsigned int* __restrict__ counts,       // [B][NSEG]
                    int A) {
    __shared__ unsigned long long lin[SEG_CAP];   // 32 KB
    __shared__ unsigned int plo[2][SEG_CAP];      // 32 KB
    __shared__ unsigned int phi[2][SEG_CAP];      // 32 KB
    __shared__ unsigned int cnt;
    const int img = blockIdx.y;
    const int seg = blockIdx.x;
    const int tid = threadIdx.x;
    const int lane = tid & 63;
    const int w = tid >> 6;                       // wave 0..7
    const float* sc = scores + (size_t)img * A;
    const unsigned int T = state[img * 2 + 0];    // exact bits of 6000th-largest score

    if (tid == 0) cnt = 0u;
    for (int i = tid; i < SEG_CAP; i += 512) lin[i] = ~0ull;  // pad keys = max
    __syncthreads();

    // compact: groups g == seg (mod NSEG), wave-aggregated LDS push
    const int ngr = A >> 6;                       // 64-element groups (2304)
    const int nj = ngr / NSEG;                    // groups per segment (576)
    for (int j = w; j < nj; j += 8) {
        int g = seg + j * NSEG;
        int i = (g << 6) + lane;
        unsigned int sv = __float_as_uint(sc[i]); // scores > 0: uint order == float order
        bool push = (sv >= T);
        unsigned long long bal = __ballot(push ? 1 : 0);
        if (push) {
            int leader = __ffsll(bal) - 1;
            int rank = __popcll(bal & ((1ull << lane) - 1ull));
            unsigned int base = 0;
            if (lane == leader) base = atomicAdd(&cnt, (unsigned int)__popcll(bal));
            base = (unsigned int)__shfl((int)base, leader);
            unsigned int pos = base + (unsigned int)rank;
            if (pos < SEG_CAP)
                lin[pos] = (((unsigned long long)(~sv)) << 32) | (unsigned long long)(unsigned int)i;
        }
    }
    __syncthreads();

    int n = (int)cnt; if (n > SEG_CAP) n = SEG_CAP;
    int P2 = 512; while (P2 < n) P2 <<= 1;        // 512..4096 (block-uniform)
    const int NT = P2 >> 3;                       // active threads
    const int t = tid;
    const bool act = (t < NT);

    unsigned long long v[8];
    if (act) {
        #pragma unroll
        for (int e = 0; e < 8; ++e) v[e] = lin[(t << 3) + e];
        // k=2,4,8 (in-register)
        CE(0,1,true) CE(2,3,false) CE(4,5,true) CE(6,7,false)
        CE(0,2,true) CE(1,3,true) CE(4,6,false) CE(5,7,false)
        CE(0,1,true) CE(2,3,true) CE(4,5,false) CE(6,7,false)
        bool u8 = ((t & 1) == 0);
        REG3(u8)
    }
    int b = 0;
    for (int k = 16; k <= P2; k <<= 1) {
        const bool up = (((t << 3) & k) == 0);
        for (int j = k >> 1; j >= 8; j >>= 1) {
            const int c = j >> 3;
            if (act) {
                #pragma unroll
                for (int e = 0; e < 8; ++e) {
                    int idx = e * NT + t;
                    plo[b][idx] = (unsigned int)v[e];
                    phi[b][idx] = (unsigned int)(v[e] >> 32);
                }
            }
            __syncthreads();
            if (act) {
                const int q = t ^ c;
                const bool keep_min = (up == ((t & c) == 0));
                #pragma unroll
                for (int e = 0; e < 8; ++e) {
                    int idx = e * NT + q;
                    unsigned long long wv = ((unsigned long long)phi[b][idx] << 32)
                                          | (unsigned long long)plo[b][idx];
                    bool less = v[e] < wv;
                    v[e] = (less == keep_min) ? v[e] : wv;
                }
            }
            b ^= 1;
        }
        if (act) { REG3(up) }
    }

    unsigned long long* gp = pool + ((size_t)img * NSEG + seg) * SEG_CAP;
    if (act) {
        #pragma unroll
        for (int e = 0; e < 8; ++e) {
            int r = (t << 3) + e;
            if (r < n) gp[r] = v[e];
        }
    }
    if (tid == 0) counts[img * NSEG + seg] = (unsigned int)n;
}

// ---------------- stage 2d: rank (merge by binary search) + decode ----------------
__global__ void __launch_bounds__(256)
rank_decode_kernel(const unsigned long long* __restrict__ pool,
                   const unsigned int* __restrict__ counts,
                   const float* __restrict__ deltas,   // [B][A][4]
                   const float* __restrict__ anchors,  // [A][4]
                   float* __restrict__ pre_boxes,      // [B][6000][4]
                   float* __restrict__ pre_scores,     // [B][6000]
                   int A) {
    __shared__ unsigned long long arr[2 * SEG_CAP];   // 64 KB (total <= 8192 fast path)
    const int img = blockIdx.y;
    const int seg = blockIdx.x;
    const int tid = threadIdx.x;

    int c[NSEG], off[NSEG + 1];
    const unsigned long long* gp[NSEG];
    off[0] = 0;
    #pragma unroll
    for (int s = 0; s < NSEG; ++s) {
        int cs = (int)counts[img * NSEG + s];
        if (cs > SEG_CAP) cs = SEG_CAP;
        c[s] = cs;
        off[s + 1] = off[s] + cs;
        gp[s] = pool + ((size_t)img * NSEG + s) * SEG_CAP;
    }
    const int total = off[NSEG];
    const bool inlds = (total <= 2 * SEG_CAP);
    if (inlds) {
        #pragma unroll
        for (int s = 0; s < NSEG; ++s)
            for (int i = tid; i < c[s]; i += 256) arr[off[s] + i] = gp[s][i];
    }
    __syncthreads();

    const int m = c[seg];
    for (int i = tid; i < m; i += 256) {
        unsigned long long key = inlds ? arr[off[seg] + i] : gp[seg][i];
        int pos = i;
        #pragma unroll
        for (int s = 0; s < NSEG; ++s) {
            if (s == seg) continue;
            const unsigned long long* base = inlds ? (arr + off[s]) : gp[s];
            int lo = 0, hi = c[s];
            while (lo < hi) {
                int mid = (lo + hi) >> 1;
                if (base[mid] < key) lo = mid + 1; else hi = mid;
            }
            pos += lo;
        }
        if (pos < PRE_N) {
            unsigned int bidx = (unsigned int)(key & 0xFFFFFFFFull);
            unsigned int sbits = ~((unsigned int)(key >> 32));
            float score = __uint_as_float(sbits);
            float a0 = anchors[(size_t)bidx * 4 + 0];
            float a1 = anchors[(size_t)bidx * 4 + 1];
            float a2 = anchors[(size_t)bidx * 4 + 2];
            float a3 = anchors[(size_t)bidx * 4 + 3];
            const float* dd = deltas + ((size_t)img * A + bidx) * 4;
            float d0 = dd[0] * 0.1f;
            float d1 = dd[1] * 0.1f;
            float d2 = dd[2] * 0.2f;
            float d3 = dd[3] * 0.2f;
            float anc_w = a3 - a1;
            float anc_h = a2 - a0;
            float anc_cx = a1 + 0.5f * anc_w;
            float anc_cy = a0 + 0.5f * anc_h;
            float bb_w = expf(d3) * anc_w;
            float bb_h = expf(d2) * anc_h;
            float bb_cx = d1 * anc_w + anc_cx;
            float bb_cy = d0 * anc_h + anc_cy;
            float y1 = bb_cy - 0.5f * bb_h;
            float x1 = bb_cx - 0.5f * bb_w;
            float y2 = bb_h + y1;
            float x2 = bb_w + x1;
            float* ob = pre_boxes + ((size_t)img * PRE_N + pos) * 4;
            ob[0] = y1; ob[1] = x1; ob[2] = y2; ob[3] = x2;
            pre_scores[(size_t)img * PRE_N + pos] = score;
        }
    }
}

// ---------------- stage 3: chunked greedy NMS (suppression-matrix resolution) ----------------
// Scores sorted desc with top_k tie order => greedy NMS == scan in index order,
// keep box j iff no previously-KEPT box suppresses it. 94 chunks of 64:
//   phase E (8 waves): chunk boxes vs kept list (LDS), early-break, ballot ->
//            atomicAnd into 64-bit ext-alive mask.
//   phase M (8 waves): 64x64 within-chunk suppression matrix; wave w computes
//            pivots i in [8w,8w+8) vs all j=lane -> partial column masks.
//            Bits i>=j are never consulted (aliveset holds only resolved lower
//            bits), so no triangle masking needed.
//   phase R (wave 0): OR partials into full columns, then a 64-step pure-ALU
//            scan: keep(i) = ext_alive[i] && (supcol[i] & aliveset)==0 && kc<300.
//            Replaces the old ~500-cycle-per-pick serial shfl chain.
__global__ void __launch_bounds__(NMS_BLOCK)
nms_kernel(const float* __restrict__ pre_boxes,
           const float* __restrict__ pre_scores,
           float* __restrict__ out_boxes,    // [B][300][4] (pre-zeroed)
           float* __restrict__ out_scores) { // [B][300]
    const int img = blockIdx.x;
    const int tid = threadIdx.x;
    const int lane = tid & 63;
    const int grp = tid >> 6;                 // 0..7
    const float4* bb4 = (const float4*)(pre_boxes + (size_t)img * PRE_N * 4);

    __shared__ float4 kept[POST_N];           // kept boxes (in keep order)
    __shared__ float  kept_area[POST_N];
    __shared__ int    kept_idx[POST_N];       // global index into pre_* arrays
    __shared__ float4 chunkbox[64];
    __shared__ unsigned long long part[8][64];  // per-wave partial column masks
    __shared__ unsigned long long supcol[64];   // full column masks
    __shared__ unsigned long long chunk_alive;  // ext-alive (phase E survivors)
    __shared__ int kept_cnt;

    if (tid == 0) kept_cnt = 0;

    const int NCH = (PRE_N + 63) >> 6;        // 94 (last chunk: 48 valid)

    // prefetch chunk 0 (grp 0 owns staging)
    float4 nb = make_float4(0.f, 0.f, 0.f, 0.f);
    if (grp == 0) nb = bb4[lane];             // chunk 0 fully valid (64 <= 6000)

    for (int c = 0; c < NCH; ++c) {
        const int base = c << 6;
        if (grp == 0) chunkbox[lane] = nb;
        if (tid == 0) {
            int rem = PRE_N - base;
            chunk_alive = (rem >= 64) ? ~0ull : ((1ull << rem) - 1ull);
        }
        __syncthreads();                      // (A) chunkbox + alive-init visible

        // issue next-chunk prefetch early; latency hides under phases E/M
        if (grp == 0 && c + 1 < NCH) {
            int j = base + 64 + lane;
            nb = (j < PRE_N) ? bb4[j] : make_float4(0.f, 0.f, 0.f, 0.f);
        }

        const int K = kept_cnt;
        float4 mb = chunkbox[lane];
        float marea = (mb.z - mb.x) * (mb.w - mb.y);

        // ---- phase E: external suppression vs previously-kept boxes ----
        bool sup = false;
        for (int k = grp; k < K; k += 8) {
            float4 pb = kept[k];              // LDS broadcast (uniform addr per wave)
            float pa = kept_area[k];
            SUPP(pb, pa, mb, marea, s)
            if (s) { sup = true; break; }
        }
        unsigned long long bal = __ballot(sup ? 1 : 0);
        if (lane == 0 && bal) atomicAnd(&chunk_alive, ~bal);

        // ---- phase M: within-chunk suppression matrix (8 pivots per wave) ----
        unsigned long long pm = 0ull;
        #pragma unroll
        for (int u = 0; u < 8; ++u) {
            const int i = (grp << 3) + u;
            float4 pb = chunkbox[i];          // uniform per iteration -> broadcast
            float pa = (pb.z - pb.x) * (pb.w - pb.y);
            SUPP(pb, pa, mb, marea, s)
            if (s) pm |= (1ull << i);
        }
        part[grp][lane] = pm;
        __syncthreads();                      // (B) chunk_alive + partials final

        // ---- phase R: wave-0 bitmask resolution ----
        if (grp == 0) {
            unsigned long long col = part[0][lane] | part[1][lane] | part[2][lane] | part[3][lane]
                                   | part[4][lane] | part[5][lane] | part[6][lane] | part[7][lane];
            supcol[lane] = col;               // same-wave write->read: LDS ops in order
            const unsigned long long extm = chunk_alive;
            unsigned long long aliveset = 0ull;
            int kc = K;
            #pragma unroll 8
            for (int i = 0; i < 64; ++i) {
                unsigned long long mi = supcol[i];   // uniform loads hoist out of chain
                bool keep = (((extm >> i) & 1ull) != 0ull) &&
                            ((mi & aliveset) == 0ull) && (kc < POST_N);
                if (keep) {                   // wave-uniform branch
                    if (lane == i) {
                        kept[kc] = mb;
                        kept_area[kc] = marea;
                        kept_idx[kc] = base + i;
                    }
                    aliveset |= (1ull << i);
                    ++kc;
                }
            }
            if (lane == 0) kept_cnt = kc;
        }
        __syncthreads();                      // (C) kept list + count visible
        if (kept_cnt >= POST_N) break;        // uniform
    }

    // ---- write outputs (rest of the pre-zeroed buffer stays zero) ----
    const int kc = kept_cnt;
    for (int r = tid; r < kc; r += NMS_BLOCK) {
        float4 bx = kept[r];
        float* ob = out_boxes + ((size_t)img * POST_N + r) * 4;
        ob[0] = bx.x; ob[1] = bx.y; ob[2] = bx.z; ob[3] = bx.w;
        out_scores[(size_t)img * POST_N + r] =
            pre_scores[(size_t)img * PRE_N + kept_idx[r]];
    }
}

extern "C" void kernel_launch(void* const* d_in, const int* in_sizes, int n_in,
                              void* d_out, int out_size, void* d_ws, size_t ws_size,
                              hipStream_t stream) {
    const float* deltas  = (const float*)d_in[0];  // (B, A, 4)
    const float* labels  = (const float*)d_in[1];  // (B, FH, FW, 9)
    const float* anchors = (const float*)d_in[2];  // (A, 4)
    float* out = (float*)d_out;

    const int A = in_sizes[2] / 4;                 // 147456
    const int B = in_sizes[0] / (A * 4);           // 32
    const int ngroups = in_sizes[1] / KCLS;        // B*FH*FW
    const int gpi = ngroups / B;                   // 16384

    // workspace layout
    float* scores     = (float*)d_ws;                                // B*A
    float* pre_boxes  = scores + (size_t)B * A;                      // B*6000*4
    float* pre_scores = pre_boxes + (size_t)B * PRE_N * 4;           // B*6000
    unsigned int* hist  = (unsigned int*)(pre_scores + (size_t)B * PRE_N);  // 3*B*2048
    unsigned int* state = hist + (size_t)3 * B * 2048;               // B*2
    unsigned long long* pool = (unsigned long long*)(state + (size_t)B * 2); // B*NSEG*SEG_CAP u64
    unsigned int* counts = (unsigned int*)(pool + (size_t)B * NSEG * SEG_CAP); // B*NSEG

    float* out_boxes  = out;                        // B*300*4
    float* out_scores = out + (size_t)B * POST_N * 4;

    hipMemsetAsync(d_out, 0, (size_t)out_size * sizeof(float), stream);
    hipMemsetAsync(hist, 0, (size_t)3 * B * 2048 * sizeof(unsigned int), stream);

    // fused softmax + radix pass-1 histogram (bits [31:21])
    softmax_hist_kernel<<<(ngroups + 255) / 256, 256, 0, stream>>>(
        labels, scores, hist + (size_t)0 * B * 2048, ngroups, gpi);
    pick_kernel<<<B, PICK_BLOCK, 0, stream>>>(hist + (size_t)0 * B * 2048, state, 21, 2048, 1);

    dim3 hgrid(CHUNKS_PER_IMG, B);
    // pass 2: bits [20:10]
    hist_kernel<<<hgrid, HIST_BLOCK, 0, stream>>>(scores, hist + (size_t)1 * B * 2048, state, A, 10, 2048, 0xFFE00000u);
    pick_kernel<<<B, PICK_BLOCK, 0, stream>>>(hist + (size_t)1 * B * 2048, state, 10, 2048, 0);
    // pass 3: bits [9:0]
    hist_kernel<<<hgrid, HIST_BLOCK, 0, stream>>>(scores, hist + (size_t)2 * B * 2048, state, A, 0, 1024, 0xFFFFFC00u);
    pick_kernel<<<B, PICK_BLOCK, 0, stream>>>(hist + (size_t)2 * B * 2048, state, 0, 1024, 0);

    dim3 sgrid(NSEG, B);
    compact_sort_kernel<<<sgrid, 512, 0, stream>>>(scores, state, pool, counts, A);
    rank_decode_kernel<<<sgrid, 256, 0, stream>>>(pool, counts, deltas, anchors,
                                                  pre_boxes, pre_scores, A);

    nms_kernel<<<B, NMS_BLOCK, 0, stream>>>(pre_boxes, pre_scores, out_boxes, out_scores);
}